// Round 6
// baseline (285.117 us; speedup 1.0000x reference)
//
#include <hip/hip_runtime.h>

typedef _Float16 f16;
typedef f16 f16x4 __attribute__((ext_vector_type(4)));
typedef f16 f16x8 __attribute__((ext_vector_type(8)));
typedef float f32x4 __attribute__((ext_vector_type(4)));

#define RES 512
#define PTS 128     // mlp: points per block
#define XS  138     // f16 stride: 69 dwords == 5 mod 32 (odd) -> <=3-way banks
#define AS  18      // f16 stride, aug region: 9 dwords (odd) -> ~2-way banks

// R16: R15's mt-slice mlp spilled to scratch: WRITE_SIZE 178MB vs 1MB actual
// output + FETCH 122MB vs ~17MB actual reads == ~300MB scratch traffic at
// 2.37TB/s == the whole 130us mlp duration. VGPR_Count 84 shows the allocator
// (pressured by __launch_bounds__(256,3)) budgeted way below the ~170 cap and
// spilled ~1 f32x4/layer/thread. Fix: (a) __launch_bounds__(256) — LDS (42KB
// -> 3 blocks/CU) is the real occupancy governor; VGPRs float to ~150, still
// 3 waves/SIMD; (b) stagger weight-fragment loads (awm per-c, awa at the aug
// block) to cut peak live range. Index math identical to the R15-passed
// kernel. Sample/pack untouched.

// ---------------------------------------------------------------- pack kernels
__device__ __forceinline__
void pack_w_body(int g, const float* __restrict__ lw, const float* __restrict__ lnw,
                 const float* __restrict__ lb, const float* __restrict__ tw1,
                 const float* __restrict__ tb1, const float* __restrict__ ivec,
                 f16* __restrict__ wf, f16* __restrict__ waugf) {
    if (g < 10240) {            // Wm fragments: 5 layers x 32 frags x 64 lanes
        const int L = g >> 11, r = g & 2047;
        const int lane = r & 63, frag = r >> 6;
        const int q = lane >> 4, l15 = lane & 15;
        const int mt = frag >> 2, c = frag & 3;
        const float* src = ((L < 4) ? (lw + L * 16384) : tw1)
                           + (mt * 16 + l15) * 128 + c * 32 + q * 8;
        f16x8 h;
        #pragma unroll
        for (int j = 0; j < 8; ++j) h[j] = (f16)src[j];
        *(f16x8*)(wf + (size_t)g * 8) = h;
    } else {                    // Waug fragments: 5 layers x 8 frags x 64 lanes
        const int ga = g - 10240;            // < 2560
        const int L = ga >> 9, r = ga & 511;
        const int lane = r & 63, mt = r >> 6;
        const int q = lane >> 4, l15 = lane & 15;
        const int row = mt * 16 + l15;
        f16x8 h = {};
        if (q == 0 && L < 4) {               // k=0..7: lnw slice
            const float* src = lnw + L * 1024 + row * 8;
            #pragma unroll
            for (int j = 0; j < 8; ++j) h[j] = (f16)src[j];
        }
        if (q == 1) {                        // k=8: bias (L0: + lw0@ivec const)
            if (L == 0) {
                float s = lb[row];
                const float4* w4 = (const float4*)(lw + row * 128);
                const float4* v4 = (const float4*)ivec;
                #pragma unroll 8
                for (int k = 0; k < 32; ++k) {
                    const float4 w = w4[k], v = v4[k];
                    s += w.x * v.x + w.y * v.y + w.z * v.z + w.w * v.w;
                }
                h[0] = (f16)s;
            } else {
                h[0] = (f16)((L < 4) ? lb[L * 128 + row] : tb1[row]);
            }
        }
        *(f16x8*)(waugf + (size_t)ga * 8) = h;
    }
}

__global__ __launch_bounds__(256)
void pack_all_k(const float* __restrict__ n, f16* __restrict__ q,
                const float* __restrict__ lw,  const float* __restrict__ lnw,
                const float* __restrict__ lb,  const float* __restrict__ tw1,
                const float* __restrict__ tb1, const float* __restrict__ ivec,
                f16* __restrict__ wf, f16* __restrict__ waugf) {
    const int b = blockIdx.x;
    if (b < 8192) {   // quad packing: one thread per 2x2 texel quad
        const int idx = b * 256 + threadIdx.x;
        const int qx = idx & 255, rest = idx >> 8;
        const int qy = rest & 255, m = rest >> 8;
        const float* src = n + ((size_t)m * 512 + 2 * qy) * 512 + 2 * qx;
        const float2 r0 = *(const float2*)(src);
        const float2 r1 = *(const float2*)(src + 512);
        f16x4 o; o[0]=(f16)r0.x; o[1]=(f16)r0.y; o[2]=(f16)r1.x; o[3]=(f16)r1.y;
        *(f16x4*)(q + (size_t)idx * 4) = o;
    } else {
        pack_w_body((b - 8192) * 256 + threadIdx.x, lw, lnw, lb, tw1, tb1, ivec, wf, waugf);
    }
}

__global__ __launch_bounds__(256)
void pack_w_k(const float* __restrict__ lw,  const float* __restrict__ lnw,
              const float* __restrict__ lb,  const float* __restrict__ tw1,
              const float* __restrict__ tb1, const float* __restrict__ ivec,
              f16* __restrict__ wf, f16* __restrict__ waugf) {
    pack_w_body(blockIdx.x * 256 + threadIdx.x, lw, lnw, lb, tw1, tb1, ivec, wf, waugf);
}

// ---------------------------------------------------------------- sample kernel
__device__ __forceinline__ float quad_tap(uint2 q, int sy, int sx) {
    unsigned w = sy ? q.y : q.x;          // row select within quad
    w >>= (sx << 4);                      // col select (low/high half)
    union { unsigned short u; f16 h; } cv; cv.u = (unsigned short)w;
    return (float)cv.h;
}

template <bool QUAD>
__global__ __launch_bounds__(256, 8)
void sample_kernel(const void* __restrict__ noise_v,
                   const float* __restrict__ coords,
                   const float* __restrict__ trans,
                   f16* __restrict__ nv_ws, const int Ntot)
{
    __shared__ float T_sh[128];
    const int t = threadIdx.x;
    if (t < 128) T_sh[t] = trans[t];
    __syncthreads();

    const int g = blockIdx.x & 7;              // feature group -> XCD pin
    const int p = (blockIdx.x >> 3) * 256 + t; // point id

    // cost-balanced plane sets (expensive planes m=9..31 split 3/..3/2)
    int mk[4];
    if (g < 7) { mk[0] = g; mk[1] = g + 9; mk[2] = g + 17; mk[3] = g + 25; }
    else       { mk[0] = 7; mk[1] = 8;     mk[2] = 16;     mk[3] = 24;     }

    const float2 c2 = *(const float2*)(coords + p * 2);

    float nvr[4];
    {
        #pragma clang fp contract(off)
        const float cx = c2.x;
        const float cy = c2.y;
        #pragma unroll
        for (int k = 0; k < 4; ++k) {
            const int m = mk[k];
            const float T00 = T_sh[m*4+0], T01 = T_sh[m*4+1];
            const float T10 = T_sh[m*4+2], T11 = T_sh[m*4+3];
            const float p0x = T00 * cx;                       // k=0: fl(cx*T00)
            const float p0y = T10 * cx;
            const float ncx = __builtin_fmaf(T01, cy, p0x);   // k=1: fused accumulate
            const float ncy = __builtin_fmaf(T11, cy, p0y);
            const float u = ncx - 0.5f;
            const float v = ncy - 0.5f;
            const float xf = floorf(u), yf = floorf(v);
            const float xw = u - xf, yw = v - yf;
            int ix = (xf >= 2147483648.0f || xf < -2147483648.0f) ? (int)(-2147483647 - 1) : (int)xf;
            int iy = (yf >= 2147483648.0f || yf < -2147483648.0f) ? (int)(-2147483647 - 1) : (int)yf;
            const int x0 = ix & (RES - 1);
            const int x1 = (int)(((unsigned)ix + 1u) & (unsigned)(RES - 1));
            const int y0 = iy & (RES - 1);
            const int y1 = (int)(((unsigned)iy + 1u) & (unsigned)(RES - 1));
            float i00, i01, i10, i11;
            if constexpr (QUAD) {
                const f16* pl = (const f16*)noise_v + (size_t)m * (256 * 256 * 4);
                const int qx0 = x0 >> 1, sx0 = x0 & 1;
                const int qx1 = x1 >> 1, sx1 = x1 & 1;
                const int qy0 = y0 >> 1, sy0 = y0 & 1;
                const int qy1 = y1 >> 1, sy1 = y1 & 1;
                const uint2 qa = *(const uint2*)(pl + (qy0 * 256 + qx0) * 4);
                const uint2 qb = *(const uint2*)(pl + (qy0 * 256 + qx1) * 4);
                const uint2 qc = *(const uint2*)(pl + (qy1 * 256 + qx0) * 4);
                const uint2 qd = *(const uint2*)(pl + (qy1 * 256 + qx1) * 4);
                i00 = quad_tap(qa, sy0, sx0);
                i01 = quad_tap(qb, sy0, sx1);
                i10 = quad_tap(qc, sy1, sx0);
                i11 = quad_tap(qd, sy1, sx1);
            } else {
                const float* pl = (const float*)noise_v + (size_t)m * (RES * RES);
                i00 = pl[y0 * RES + x0];
                i01 = pl[y0 * RES + x1];
                i10 = pl[y1 * RES + x0];
                i11 = pl[y1 * RES + x1];
            }
            const float a0 = i00 + (i01 - i00) * xw;
            const float a1 = i10 + (i11 - i10) * xw;
            nvr[k] = a0 + (a1 - a0) * yw;
        }
    }
    #pragma unroll
    for (int k = 0; k < 4; ++k) {              // nv slot(m) = (m&7)*4 + (m>>3)
        const int m = mk[k];
        const int slot = (m & 7) * 4 + (m >> 3);
        nv_ws[(size_t)slot * Ntot + p] = (f16)nvr[k];
    }
}

// ---------------------------------------------------------------- mlp kernel
__global__ __launch_bounds__(256)
void mlp_kernel(const f16* __restrict__ nv_ws,
                const f16* __restrict__ wf,
                const f16* __restrict__ waugf,
                const float* __restrict__ tw2,
                const float* __restrict__ tb2,
                float* __restrict__ out, const int Ntot)
{
    __shared__ f16 xa[PTS * XS];        // 35328 B  activations [pt][feat]
    __shared__ f16 xaug[PTS * AS];      //  4608 B  [nv(8) | bias=1 | zeros(7)]
    __shared__ float pp[4][PTS];        //  2048 B  head partials per wave

    const int t    = threadIdx.x;
    const int wave = t >> 6;            // wave owns feature rows [wave*32, +32)
    const int lane = t & 63;
    const int q    = lane >> 4;
    const int l15  = lane & 15;
    const int pbase = blockIdx.x * PTS;
    const int p = t >> 1, h = t & 1;    // 2 threads per point (nv ownership)

    // ---------------- init ----------------
    if (t < 128) {
        xaug[t * AS + 8] = (f16)1.0f;          // bias lane
        #pragma unroll
        for (int c = 9; c < 16; ++c) xaug[t * AS + c] = (f16)0.0f;
    }
    const float tb2_0 = tb2[0];

    // nv gather: feat 16h+j = plane j*4+2h; coalesced scalar loads.
    f16x8 nva, nvb;
    {
        const int P = pbase + p;
        #pragma unroll
        for (int j = 0; j < 8; ++j) {
            nva[j] = nv_ws[(size_t)(j * 4 + 2 * h)     * Ntot + P];
            nvb[j] = nv_ws[(size_t)(j * 4 + 2 * h + 1) * Ntot + P];
        }
    }
    if (h == 0) *(f16x8*)&xaug[p * AS] = nva;   // layer-0 feats 0..7
    __syncthreads();   // init + L0 aug rows visible to all waves

    // ---------------- 5 MFMA layers (L0 = aug-only; main folded into c0) ----
    f32x4 acc[2][8];
    #pragma unroll 1
    for (int L = 0; L < 5; ++L) {
        {
            const f32x4 z4 = {0.f, 0.f, 0.f, 0.f};
            #pragma unroll
            for (int mtl = 0; mtl < 2; ++mtl)
                #pragma unroll
                for (int pt = 0; pt < 8; ++pt) acc[mtl][pt] = z4;
        }
        if (L) {
            #pragma unroll
            for (int c = 0; c < 4; ++c) {   // main K=128; weights per-c from L2
                const f16x8 awm0 = *(const f16x8*)
                    &wf[(size_t)((L * 32 + (wave * 2 + 0) * 4 + c) * 64 + lane) * 8];
                const f16x8 awm1 = *(const f16x8*)
                    &wf[(size_t)((L * 32 + (wave * 2 + 1) * 4 + c) * 64 + lane) * 8];
                const int kc = c * 32 + q * 8;
                #pragma unroll
                for (int pt = 0; pt < 8; ++pt) {
                    const f16x8 xb = *(const f16x8*)&xa[(pt * 16 + l15) * XS + kc];
                    acc[0][pt] = __builtin_amdgcn_mfma_f32_16x16x32_f16(awm0, xb, acc[0][pt], 0, 0, 0);
                    acc[1][pt] = __builtin_amdgcn_mfma_f32_16x16x32_f16(awm1, xb, acc[1][pt], 0, 0, 0);
                }
            }
        }
        {   // aug chunk: A-side fully stored (zeros for q>=2), B-side exec-masked
            const f16x8 awa0 = *(const f16x8*)
                &waugf[(size_t)((L * 8 + wave * 2 + 0) * 64 + lane) * 8];
            const f16x8 awa1 = *(const f16x8*)
                &waugf[(size_t)((L * 8 + wave * 2 + 1) * 64 + lane) * 8];
            #pragma unroll
            for (int pt = 0; pt < 8; ++pt) {
                f16x8 xb = {};
                if (q < 2) xb = *(const f16x8*)&xaug[(pt * 16 + l15) * AS + q * 8];
                acc[0][pt] = __builtin_amdgcn_mfma_f32_16x16x32_f16(awa0, xb, acc[0][pt], 0, 0, 0);
                acc[1][pt] = __builtin_amdgcn_mfma_f32_16x16x32_f16(awa1, xb, acc[1][pt], 0, 0, 0);
            }
        }

        __syncthreads();   // all waves done READING xa/xaug for layer L

        if (L < 4) {
            // epilogue: leaky-relu + pack into this wave's feature-column slice
            #pragma unroll
            for (int mtl = 0; mtl < 2; ++mtl) {
                const int fc = wave * 32 + mtl * 16 + q * 4;
                #pragma unroll
                for (int pt = 0; pt < 8; ++pt) {
                    f16x4 hv;
                    #pragma unroll
                    for (int r = 0; r < 4; ++r) {
                        float v = acc[mtl][pt][r];
                        v = fmaxf(v, 0.01f * v);
                        hv[r] = (f16)v;
                    }
                    *(f16x4*)&xa[(pt * 16 + l15) * XS + fc] = hv;
                }
            }
            if (L < 3) {   // next layer's nv into xaug (owning thread)
                const int Ln = L + 1;
                if ((Ln >> 1) == h)
                    *(f16x8*)&xaug[p * AS] = (Ln & 1) ? nvb : nva;
            }
            __syncthreads();   // writes visible before next layer's reads
        } else {
            // head: partial dot over this wave's 32 features; combine via LDS
            const f32x4 w40 = *(const f32x4*)&tw2[wave * 32 + q * 4];
            const f32x4 w41 = *(const f32x4*)&tw2[wave * 32 + 16 + q * 4];
            #pragma unroll
            for (int pt = 0; pt < 8; ++pt) {
                float s = 0.f;
                #pragma unroll
                for (int r = 0; r < 4; ++r) {
                    float v0 = acc[0][pt][r];
                    v0 = fmaxf(v0, 0.01f * v0);
                    float v1 = acc[1][pt][r];
                    v1 = fmaxf(v1, 0.01f * v1);
                    s += w40[r] * v0 + w41[r] * v1;
                }
                s += __shfl_xor(s, 16);
                s += __shfl_xor(s, 32);
                if (q == 0) pp[wave][pt * 16 + l15] = s;
            }
            __syncthreads();
            if (t < 128)
                out[pbase + t] = pp[0][t] + pp[1][t] + pp[2][t] + pp[3][t] + tb2_0;
        }
    }
}

extern "C" void kernel_launch(void* const* d_in, const int* in_sizes, int n_in,
                              void* d_out, int out_size, void* d_ws, size_t ws_size,
                              hipStream_t stream) {
    const float* noise  = (const float*)d_in[0];
    const float* coords = (const float*)d_in[1];
    const float* trans  = (const float*)d_in[2];
    const float* ivec   = (const float*)d_in[3];
    const float* lw     = (const float*)d_in[4];
    const float* lb     = (const float*)d_in[5];
    const float* lnw    = (const float*)d_in[6];
    const float* tw1    = (const float*)d_in[7];
    const float* tb1    = (const float*)d_in[8];
    const float* tw2    = (const float*)d_in[9];
    const float* tb2    = (const float*)d_in[10];
    float* o            = (float*)d_out;

    const int N = in_sizes[1] / 2;                    // coords is [N,2]
    // ws layout: nv [32 planes][N] f16 (16 MiB) | wf | waug | quads (16 MiB)
    f16* nv    = (f16*)d_ws;
    const size_t NV = (size_t)N * 32;                 // f16 units
    f16* wfp   = nv + NV;
    f16* waugp = wfp + 5 * 16384;
    f16* qn    = waugp + 5 * 4096;
    const size_t need_full = (NV + 5 * 16384 + 5 * 4096
                              + (size_t)32 * 256 * 256 * 4) * sizeof(f16);

    if (ws_size >= need_full) {   // ws_size constant across calls -> graph-safe
        pack_all_k<<<8192 + 50, 256, 0, stream>>>(noise, qn, lw, lnw, lb, tw1, tb1,
                                                  ivec, wfp, waugp);
        sample_kernel<true><<<(N / 256) * 8, 256, 0, stream>>>(qn, coords, trans, nv, N);
    } else {
        pack_w_k<<<50, 256, 0, stream>>>(lw, lnw, lb, tw1, tb1, ivec, wfp, waugp);
        sample_kernel<false><<<(N / 256) * 8, 256, 0, stream>>>(noise, coords, trans, nv, N);
    }
    mlp_kernel<<<N / PTS, 256, 0, stream>>>(nv, wfp, waugp, tw2, tb2, o, N);
}

// Round 7
// 220.897 us; speedup vs baseline: 1.2907x; 1.2907x over previous
//
#include <hip/hip_runtime.h>

typedef _Float16 f16;
typedef f16 f16x4 __attribute__((ext_vector_type(4)));
typedef f16 f16x8 __attribute__((ext_vector_type(8)));
typedef float f32x4 __attribute__((ext_vector_type(4)));

#define RES 512
#define PTS 128     // mlp: points per block (4 waves x 32 pts)
#define XS  138     // f16 stride: 69 dwords == 5 mod 32 (odd) -> <=3-way banks
#define AS  18      // f16 stride, aug region: 9 dwords (odd) -> ~2-way banks

// R17: mt-slice (R15/R16) abandoned — even spill-free it ran 132us at 11% occ
// (1 block/CU, ~1 wave/SIMD: zero TLP, every L2/LDS/barrier latency exposed).
// Revert mlp to the R13-verified pt-slice staged design (2 blocks/CU, ~63us)
// + ONE change: T14 async-stage split. R13 staged weights INSIDE the barrier
// pair (barrier -> 40KB L2->reg->LDS -> barrier -> compute), exposing the L2
// fetch latency. Now: next-layer weight loads issue at the TOP of layer L
// (latency hides under L's MFMAs/epilogue); after the read-done barrier only
// the cheap ds_writes + barrier remain. Same 2 barriers/layer. xa/xaug are
// wave-private (R13-verified) so barriers still only protect Wm/Waug.
// +40 VGPRs in flight (10 f16x8) on R13's 96 -> ~150 < 256 cap at (256,2).
// Sample/pack unchanged (sample 72us: L2-request/MSHR-bound, separate fight).

// ---------------------------------------------------------------- pack kernels
__device__ __forceinline__
void pack_w_body(int g, const float* __restrict__ lw, const float* __restrict__ lnw,
                 const float* __restrict__ lb, const float* __restrict__ tw1,
                 const float* __restrict__ tb1, const float* __restrict__ ivec,
                 f16* __restrict__ wf, f16* __restrict__ waugf) {
    if (g < 10240) {            // Wm fragments: 5 layers x 32 frags x 64 lanes
        const int L = g >> 11, r = g & 2047;
        const int lane = r & 63, frag = r >> 6;
        const int q = lane >> 4, l15 = lane & 15;
        const int mt = frag >> 2, c = frag & 3;
        const float* src = ((L < 4) ? (lw + L * 16384) : tw1)
                           + (mt * 16 + l15) * 128 + c * 32 + q * 8;
        f16x8 h;
        #pragma unroll
        for (int j = 0; j < 8; ++j) h[j] = (f16)src[j];
        *(f16x8*)(wf + (size_t)g * 8) = h;
    } else {                    // Waug fragments: 5 layers x 8 frags x 64 lanes
        const int ga = g - 10240;            // < 2560
        const int L = ga >> 9, r = ga & 511;
        const int lane = r & 63, mt = r >> 6;
        const int q = lane >> 4, l15 = lane & 15;
        const int row = mt * 16 + l15;
        f16x8 h = {};
        if (q == 0 && L < 4) {               // k=0..7: lnw slice
            const float* src = lnw + L * 1024 + row * 8;
            #pragma unroll
            for (int j = 0; j < 8; ++j) h[j] = (f16)src[j];
        }
        if (q == 1) {                        // k=8: bias (L0: + lw0@ivec const)
            if (L == 0) {
                float s = lb[row];
                const float4* w4 = (const float4*)(lw + row * 128);
                const float4* v4 = (const float4*)ivec;
                #pragma unroll 8
                for (int k = 0; k < 32; ++k) {
                    const float4 w = w4[k], v = v4[k];
                    s += w.x * v.x + w.y * v.y + w.z * v.z + w.w * v.w;
                }
                h[0] = (f16)s;
            } else {
                h[0] = (f16)((L < 4) ? lb[L * 128 + row] : tb1[row]);
            }
        }
        *(f16x8*)(waugf + (size_t)ga * 8) = h;
    }
}

__global__ __launch_bounds__(256)
void pack_all_k(const float* __restrict__ n, f16* __restrict__ q,
                const float* __restrict__ lw,  const float* __restrict__ lnw,
                const float* __restrict__ lb,  const float* __restrict__ tw1,
                const float* __restrict__ tb1, const float* __restrict__ ivec,
                f16* __restrict__ wf, f16* __restrict__ waugf) {
    const int b = blockIdx.x;
    if (b < 8192) {   // quad packing: one thread per 2x2 texel quad
        const int idx = b * 256 + threadIdx.x;
        const int qx = idx & 255, rest = idx >> 8;
        const int qy = rest & 255, m = rest >> 8;
        const float* src = n + ((size_t)m * 512 + 2 * qy) * 512 + 2 * qx;
        const float2 r0 = *(const float2*)(src);
        const float2 r1 = *(const float2*)(src + 512);
        f16x4 o; o[0]=(f16)r0.x; o[1]=(f16)r0.y; o[2]=(f16)r1.x; o[3]=(f16)r1.y;
        *(f16x4*)(q + (size_t)idx * 4) = o;
    } else {
        pack_w_body((b - 8192) * 256 + threadIdx.x, lw, lnw, lb, tw1, tb1, ivec, wf, waugf);
    }
}

__global__ __launch_bounds__(256)
void pack_w_k(const float* __restrict__ lw,  const float* __restrict__ lnw,
              const float* __restrict__ lb,  const float* __restrict__ tw1,
              const float* __restrict__ tb1, const float* __restrict__ ivec,
              f16* __restrict__ wf, f16* __restrict__ waugf) {
    pack_w_body(blockIdx.x * 256 + threadIdx.x, lw, lnw, lb, tw1, tb1, ivec, wf, waugf);
}

// ---------------------------------------------------------------- sample kernel
__device__ __forceinline__ float quad_tap(uint2 q, int sy, int sx) {
    unsigned w = sy ? q.y : q.x;          // row select within quad
    w >>= (sx << 4);                      // col select (low/high half)
    union { unsigned short u; f16 h; } cv; cv.u = (unsigned short)w;
    return (float)cv.h;
}

template <bool QUAD>
__global__ __launch_bounds__(256, 8)
void sample_kernel(const void* __restrict__ noise_v,
                   const float* __restrict__ coords,
                   const float* __restrict__ trans,
                   f16* __restrict__ nv_ws, const int Ntot)
{
    __shared__ float T_sh[128];
    const int t = threadIdx.x;
    if (t < 128) T_sh[t] = trans[t];
    __syncthreads();

    const int g = blockIdx.x & 7;              // feature group -> XCD pin
    const int p = (blockIdx.x >> 3) * 256 + t; // point id

    // cost-balanced plane sets (expensive planes m=9..31 split 3/..3/2)
    int mk[4];
    if (g < 7) { mk[0] = g; mk[1] = g + 9; mk[2] = g + 17; mk[3] = g + 25; }
    else       { mk[0] = 7; mk[1] = 8;     mk[2] = 16;     mk[3] = 24;     }

    const float2 c2 = *(const float2*)(coords + p * 2);

    float nvr[4];
    {
        #pragma clang fp contract(off)
        const float cx = c2.x;
        const float cy = c2.y;
        #pragma unroll
        for (int k = 0; k < 4; ++k) {
            const int m = mk[k];
            const float T00 = T_sh[m*4+0], T01 = T_sh[m*4+1];
            const float T10 = T_sh[m*4+2], T11 = T_sh[m*4+3];
            const float p0x = T00 * cx;                       // k=0: fl(cx*T00)
            const float p0y = T10 * cx;
            const float ncx = __builtin_fmaf(T01, cy, p0x);   // k=1: fused accumulate
            const float ncy = __builtin_fmaf(T11, cy, p0y);
            const float u = ncx - 0.5f;
            const float v = ncy - 0.5f;
            const float xf = floorf(u), yf = floorf(v);
            const float xw = u - xf, yw = v - yf;
            int ix = (xf >= 2147483648.0f || xf < -2147483648.0f) ? (int)(-2147483647 - 1) : (int)xf;
            int iy = (yf >= 2147483648.0f || yf < -2147483648.0f) ? (int)(-2147483647 - 1) : (int)yf;
            const int x0 = ix & (RES - 1);
            const int x1 = (int)(((unsigned)ix + 1u) & (unsigned)(RES - 1));
            const int y0 = iy & (RES - 1);
            const int y1 = (int)(((unsigned)iy + 1u) & (unsigned)(RES - 1));
            float i00, i01, i10, i11;
            if constexpr (QUAD) {
                const f16* pl = (const f16*)noise_v + (size_t)m * (256 * 256 * 4);
                const int qx0 = x0 >> 1, sx0 = x0 & 1;
                const int qx1 = x1 >> 1, sx1 = x1 & 1;
                const int qy0 = y0 >> 1, sy0 = y0 & 1;
                const int qy1 = y1 >> 1, sy1 = y1 & 1;
                const uint2 qa = *(const uint2*)(pl + (qy0 * 256 + qx0) * 4);
                const uint2 qb = *(const uint2*)(pl + (qy0 * 256 + qx1) * 4);
                const uint2 qc = *(const uint2*)(pl + (qy1 * 256 + qx0) * 4);
                const uint2 qd = *(const uint2*)(pl + (qy1 * 256 + qx1) * 4);
                i00 = quad_tap(qa, sy0, sx0);
                i01 = quad_tap(qb, sy0, sx1);
                i10 = quad_tap(qc, sy1, sx0);
                i11 = quad_tap(qd, sy1, sx1);
            } else {
                const float* pl = (const float*)noise_v + (size_t)m * (RES * RES);
                i00 = pl[y0 * RES + x0];
                i01 = pl[y0 * RES + x1];
                i10 = pl[y1 * RES + x0];
                i11 = pl[y1 * RES + x1];
            }
            const float a0 = i00 + (i01 - i00) * xw;
            const float a1 = i10 + (i11 - i10) * xw;
            nvr[k] = a0 + (a1 - a0) * yw;
        }
    }
    #pragma unroll
    for (int k = 0; k < 4; ++k) {              // nv slot(m) = (m&7)*4 + (m>>3)
        const int m = mk[k];
        const int slot = (m & 7) * 4 + (m >> 3);
        nv_ws[(size_t)slot * Ntot + p] = (f16)nvr[k];
    }
}

// ---------------------------------------------------------------- mlp kernel
__global__ __launch_bounds__(256, 2)
void mlp_kernel(const f16* __restrict__ nv_ws,
                const f16* __restrict__ wf,
                const f16* __restrict__ waugf,
                const float* __restrict__ tw2,
                const float* __restrict__ tb2,
                float* __restrict__ out, const int Ntot)
{
    __shared__ f16 Wm[16384];           // 32 frags x 512 f16 = 32768 B, lane-linear
    __shared__ f16 Waug[4096];          //  8 frags x 512 f16 =  8192 B
    __shared__ f16 xa[PTS * XS];        // 35328 B
    __shared__ f16 xaug[PTS * AS];      //  4608 B
    __shared__ __align__(16) float tw2_sh[128];   // 512 B; total 81408 B

    const int t    = threadIdx.x;
    const int wave = t >> 6;
    const int lane = t & 63;
    const int q    = lane >> 4;
    const int l15  = lane & 15;
    const int pbase = blockIdx.x * PTS;
    const int pw    = wave * 32;        // wave-private point rows [pw, pw+32)
    const int p = t >> 1, h = t & 1;    // 2 threads per point (nv ownership)

    // ---------------- init ----------------
    if (t < 128) {
        tw2_sh[t] = tw2[t];
        xaug[t * AS + 8] = (f16)1.0f;          // bias lane
        #pragma unroll
        for (int c = 9; c < 16; ++c) xaug[t * AS + c] = (f16)0.0f;
    }
    const float tb2_0 = tb2[0];

    // nv gather: feat 16h+j = plane j*4+2h; coalesced scalar loads.
    f16x8 nva, nvb;
    {
        const int P = pbase + p;
        #pragma unroll
        for (int j = 0; j < 8; ++j) {
            nva[j] = nv_ws[(size_t)(j * 4 + 2 * h)     * Ntot + P];
            nvb[j] = nv_ws[(size_t)(j * 4 + 2 * h + 1) * Ntot + P];
        }
    }
    if (h == 0) *(f16x8*)&xaug[p * AS] = nva;   // layer-0 feats 0..7 (same-wave reader)

    // prologue: stage L0's Waug (Wm[0] unused — L0 main folded into c0 bias)
    {
        const f16x8 a0 = *(const f16x8*)&waugf[t * 8];
        const f16x8 a1 = *(const f16x8*)&waugf[(t + 256) * 8];
        *(f16x8*)&Waug[t * 8]         = a0;
        *(f16x8*)&Waug[(t + 256) * 8] = a1;
    }
    __syncthreads();   // init + L0 aug rows + L0 Waug visible to all waves

    // ---------------- 5 MFMA layers (L0 = aug-only) ----------------
    f32x4 acc[2][8];
    f16x8 wreg[8], areg[2];             // T14: next-layer weights in flight
    #pragma unroll 1
    for (int L = 0; L < 5; ++L) {
        if (L < 4) {   // issue L+1 weight loads NOW; latency hides under compute
            const f16* wsrc = wf + (L + 1) * 16384;
            #pragma unroll
            for (int i = 0; i < 8; ++i)
                wreg[i] = *(const f16x8*)&wsrc[(t + i * 256) * 8];
            const f16* asrc = waugf + (L + 1) * 4096;
            areg[0] = *(const f16x8*)&asrc[t * 8];
            areg[1] = *(const f16x8*)&asrc[(t + 256) * 8];
        }

        {
            const f32x4 z4 = {0.f, 0.f, 0.f, 0.f};
            #pragma unroll
            for (int i = 0; i < 2; ++i)
                #pragma unroll
                for (int mt = 0; mt < 8; ++mt) acc[i][mt] = z4;
        }
        const int pr0 = (pw + l15) * XS, pr1 = (pw + 16 + l15) * XS;
        if (L) {
            #pragma unroll
            for (int c = 0; c < 4; ++c) {   // main K=128
                const int kc = c * 32 + q * 8;
                const f16x8 xb0 = *(const f16x8*)&xa[pr0 + kc];
                const f16x8 xb1 = *(const f16x8*)&xa[pr1 + kc];
                #pragma unroll
                for (int mt = 0; mt < 8; ++mt) {
                    const f16x8 aw = *(const f16x8*)&Wm[((mt * 4 + c) * 64 + lane) * 8]; // conflict-free
                    acc[0][mt] = __builtin_amdgcn_mfma_f32_16x16x32_f16(aw, xb0, acc[0][mt], 0, 0, 0);
                    acc[1][mt] = __builtin_amdgcn_mfma_f32_16x16x32_f16(aw, xb1, acc[1][mt], 0, 0, 0);
                }
            }
        }
        {   // aug chunk: A-side fully stored (zeros for q>=2), B-side exec-masked
            f16x8 xb0 = {}, xb1 = {};
            if (q < 2) {
                xb0 = *(const f16x8*)&xaug[(pw + l15) * AS + q * 8];
                xb1 = *(const f16x8*)&xaug[(pw + 16 + l15) * AS + q * 8];
            }
            #pragma unroll
            for (int mt = 0; mt < 8; ++mt) {
                const f16x8 aw = *(const f16x8*)&Waug[(mt * 64 + lane) * 8];
                acc[0][mt] = __builtin_amdgcn_mfma_f32_16x16x32_f16(aw, xb0, acc[0][mt], 0, 0, 0);
                acc[1][mt] = __builtin_amdgcn_mfma_f32_16x16x32_f16(aw, xb1, acc[1][mt], 0, 0, 0);
            }
        }

        if (L < 4) {
            // epilogue: leaky-relu + pack; wave-private xa rows -> no barrier
            #pragma unroll
            for (int i = 0; i < 2; ++i) {
                const int pr = (pw + i * 16 + l15) * XS;
                #pragma unroll
                for (int mt = 0; mt < 8; ++mt) {
                    f16x4 hv;
                    #pragma unroll
                    for (int r = 0; r < 4; ++r) {
                        float v = acc[i][mt][r];
                        v = fmaxf(v, 0.01f * v);
                        hv[r] = (f16)v;
                    }
                    *(f16x4*)&xa[pr + mt * 16 + q * 4] = hv;
                }
            }
            if (L < 3) {   // next layer's nv into xaug (owning thread; same-wave reader)
                const int Ln = L + 1;
                if ((Ln >> 1) == h)
                    *(f16x8*)&xaug[p * AS] = (Ln & 1) ? nvb : nva;
            }
            __syncthreads();   // all waves done READING Wm/Waug for layer L
            {   // write the prefetched L+1 weights (loads long since landed)
                #pragma unroll
                for (int i = 0; i < 8; ++i)
                    *(f16x8*)&Wm[(t + i * 256) * 8] = wreg[i];
                *(f16x8*)&Waug[t * 8]         = areg[0];
                *(f16x8*)&Waug[(t + 256) * 8] = areg[1];
            }
            __syncthreads();   // staged weights visible for layer L+1
        } else {
            // head: out = tw2 . lrelu(h) + tb2; butterfly over quads
            #pragma unroll
            for (int i = 0; i < 2; ++i) {
                float s = 0.f;
                #pragma unroll
                for (int mt = 0; mt < 8; ++mt) {
                    const f32x4 w4 = *(const f32x4*)&tw2_sh[mt * 16 + q * 4];
                    #pragma unroll
                    for (int r = 0; r < 4; ++r) {
                        float v = acc[i][mt][r];
                        v = fmaxf(v, 0.01f * v);
                        s += w4[r] * v;
                    }
                }
                s += __shfl_xor(s, 16);
                s += __shfl_xor(s, 32);
                if (q == 0) out[pbase + pw + i * 16 + l15] = s + tb2_0;
            }
        }
    }
}

extern "C" void kernel_launch(void* const* d_in, const int* in_sizes, int n_in,
                              void* d_out, int out_size, void* d_ws, size_t ws_size,
                              hipStream_t stream) {
    const float* noise  = (const float*)d_in[0];
    const float* coords = (const float*)d_in[1];
    const float* trans  = (const float*)d_in[2];
    const float* ivec   = (const float*)d_in[3];
    const float* lw     = (const float*)d_in[4];
    const float* lb     = (const float*)d_in[5];
    const float* lnw    = (const float*)d_in[6];
    const float* tw1    = (const float*)d_in[7];
    const float* tb1    = (const float*)d_in[8];
    const float* tw2    = (const float*)d_in[9];
    const float* tb2    = (const float*)d_in[10];
    float* o            = (float*)d_out;

    const int N = in_sizes[1] / 2;                    // coords is [N,2]
    // ws layout: nv [32 planes][N] f16 (16 MiB) | wf | waug | quads (16 MiB)
    f16* nv    = (f16*)d_ws;
    const size_t NV = (size_t)N * 32;                 // f16 units
    f16* wfp   = nv + NV;
    f16* waugp = wfp + 5 * 16384;
    f16* qn    = waugp + 5 * 4096;
    const size_t need_full = (NV + 5 * 16384 + 5 * 4096
                              + (size_t)32 * 256 * 256 * 4) * sizeof(f16);

    if (ws_size >= need_full) {   // ws_size constant across calls -> graph-safe
        pack_all_k<<<8192 + 50, 256, 0, stream>>>(noise, qn, lw, lnw, lb, tw1, tb1,
                                                  ivec, wfp, waugp);
        sample_kernel<true><<<(N / 256) * 8, 256, 0, stream>>>(qn, coords, trans, nv, N);
    } else {
        pack_w_k<<<50, 256, 0, stream>>>(lw, lnw, lb, tw1, tb1, ivec, wfp, waugp);
        sample_kernel<false><<<(N / 256) * 8, 256, 0, stream>>>(noise, coords, trans, nv, N);
    }
    mlp_kernel<<<N / PTS, 256, 0, stream>>>(nv, wfp, waugp, tw2, tb2, o, N);
}

// Round 8
// 209.435 us; speedup vs baseline: 1.3614x; 1.0547x over previous
//
#include <hip/hip_runtime.h>

typedef _Float16 f16;
typedef f16 f16x4 __attribute__((ext_vector_type(4)));
typedef f16 f16x8 __attribute__((ext_vector_type(8)));
typedef float f32x4 __attribute__((ext_vector_type(4)));

#define RES 512
#define PTS 128     // mlp: points per block (4 waves x 32 pts)
#define XS  138     // f16 stride: 69 dwords == 5 mod 32 (odd) -> <=3-way banks
#define AS  18      // f16 stride, aug region: 9 dwords (odd) -> ~2-way banks

// R18: sample ILP probe. Sample is latency-bound (VALU 17%, occ 66%, HBM 5%,
// FETCH 13.7MB L2-hot): throughput = outstanding-reqs/latency. Discriminating
// experiment: 4 points/thread (16 samples, 64 independent 8B loads), grid
// 8192->2048 blocks, launch_bounds(256,4). If per-CU outstanding-slot bound
// (TLP x ILP), dur 72->~57; if L1-MSHR-line bound, null -> sample is at its
// structural floor and mlp surfaces in top-5 for the first post-R17 read.
// Sampling math chain verbatim per (point,feat); pack + mlp byte-identical to
// R17 (passed, 220.9us). Rejected this round: sample-into-mlp fusion (loses
// XCD pinning; ~420MB L2-out at ~3TB/s LLC ceiling = 140us — worse).

// ---------------------------------------------------------------- pack kernels
__device__ __forceinline__
void pack_w_body(int g, const float* __restrict__ lw, const float* __restrict__ lnw,
                 const float* __restrict__ lb, const float* __restrict__ tw1,
                 const float* __restrict__ tb1, const float* __restrict__ ivec,
                 f16* __restrict__ wf, f16* __restrict__ waugf) {
    if (g < 10240) {            // Wm fragments: 5 layers x 32 frags x 64 lanes
        const int L = g >> 11, r = g & 2047;
        const int lane = r & 63, frag = r >> 6;
        const int q = lane >> 4, l15 = lane & 15;
        const int mt = frag >> 2, c = frag & 3;
        const float* src = ((L < 4) ? (lw + L * 16384) : tw1)
                           + (mt * 16 + l15) * 128 + c * 32 + q * 8;
        f16x8 h;
        #pragma unroll
        for (int j = 0; j < 8; ++j) h[j] = (f16)src[j];
        *(f16x8*)(wf + (size_t)g * 8) = h;
    } else {                    // Waug fragments: 5 layers x 8 frags x 64 lanes
        const int ga = g - 10240;            // < 2560
        const int L = ga >> 9, r = ga & 511;
        const int lane = r & 63, mt = r >> 6;
        const int q = lane >> 4, l15 = lane & 15;
        const int row = mt * 16 + l15;
        f16x8 h = {};
        if (q == 0 && L < 4) {               // k=0..7: lnw slice
            const float* src = lnw + L * 1024 + row * 8;
            #pragma unroll
            for (int j = 0; j < 8; ++j) h[j] = (f16)src[j];
        }
        if (q == 1) {                        // k=8: bias (L0: + lw0@ivec const)
            if (L == 0) {
                float s = lb[row];
                const float4* w4 = (const float4*)(lw + row * 128);
                const float4* v4 = (const float4*)ivec;
                #pragma unroll 8
                for (int k = 0; k < 32; ++k) {
                    const float4 w = w4[k], v = v4[k];
                    s += w.x * v.x + w.y * v.y + w.z * v.z + w.w * v.w;
                }
                h[0] = (f16)s;
            } else {
                h[0] = (f16)((L < 4) ? lb[L * 128 + row] : tb1[row]);
            }
        }
        *(f16x8*)(waugf + (size_t)ga * 8) = h;
    }
}

__global__ __launch_bounds__(256)
void pack_all_k(const float* __restrict__ n, f16* __restrict__ q,
                const float* __restrict__ lw,  const float* __restrict__ lnw,
                const float* __restrict__ lb,  const float* __restrict__ tw1,
                const float* __restrict__ tb1, const float* __restrict__ ivec,
                f16* __restrict__ wf, f16* __restrict__ waugf) {
    const int b = blockIdx.x;
    if (b < 8192) {   // quad packing: one thread per 2x2 texel quad
        const int idx = b * 256 + threadIdx.x;
        const int qx = idx & 255, rest = idx >> 8;
        const int qy = rest & 255, m = rest >> 8;
        const float* src = n + ((size_t)m * 512 + 2 * qy) * 512 + 2 * qx;
        const float2 r0 = *(const float2*)(src);
        const float2 r1 = *(const float2*)(src + 512);
        f16x4 o; o[0]=(f16)r0.x; o[1]=(f16)r0.y; o[2]=(f16)r1.x; o[3]=(f16)r1.y;
        *(f16x4*)(q + (size_t)idx * 4) = o;
    } else {
        pack_w_body((b - 8192) * 256 + threadIdx.x, lw, lnw, lb, tw1, tb1, ivec, wf, waugf);
    }
}

__global__ __launch_bounds__(256)
void pack_w_k(const float* __restrict__ lw,  const float* __restrict__ lnw,
              const float* __restrict__ lb,  const float* __restrict__ tw1,
              const float* __restrict__ tb1, const float* __restrict__ ivec,
              f16* __restrict__ wf, f16* __restrict__ waugf) {
    pack_w_body(blockIdx.x * 256 + threadIdx.x, lw, lnw, lb, tw1, tb1, ivec, wf, waugf);
}

// ---------------------------------------------------------------- sample kernel
__device__ __forceinline__ float quad_tap(uint2 q, int sy, int sx) {
    unsigned w = sy ? q.y : q.x;          // row select within quad
    w >>= (sx << 4);                      // col select (low/high half)
    union { unsigned short u; f16 h; } cv; cv.u = (unsigned short)w;
    return (float)cv.h;
}

template <bool QUAD>
__global__ __launch_bounds__(256, 4)
void sample_kernel(const void* __restrict__ noise_v,
                   const float* __restrict__ coords,
                   const float* __restrict__ trans,
                   f16* __restrict__ nv_ws, const int Ntot)
{
    __shared__ float T_sh[128];
    const int t = threadIdx.x;
    if (t < 128) T_sh[t] = trans[t];
    __syncthreads();

    const int g = blockIdx.x & 7;                     // feature group -> XCD pin
    const int pb = (blockIdx.x >> 3) * 1024 + t;      // 4 points: pb + 256*j

    // cost-balanced plane sets (expensive planes m=9..31 split 3/..3/2)
    int mk[4];
    if (g < 7) { mk[0] = g; mk[1] = g + 9; mk[2] = g + 17; mk[3] = g + 25; }
    else       { mk[0] = 7; mk[1] = 8;     mk[2] = 16;     mk[3] = 24;     }

    float2 c[4];
    #pragma unroll
    for (int j = 0; j < 4; ++j)
        c[j] = *(const float2*)(coords + (pb + 256 * j) * 2);

    float nvr[4][4];
    {
        #pragma clang fp contract(off)
        #pragma unroll
        for (int j = 0; j < 4; ++j) {
            const float cx = c[j].x;
            const float cy = c[j].y;
            #pragma unroll
            for (int k = 0; k < 4; ++k) {
                const int m = mk[k];
                const float T00 = T_sh[m*4+0], T01 = T_sh[m*4+1];
                const float T10 = T_sh[m*4+2], T11 = T_sh[m*4+3];
                const float p0x = T00 * cx;                       // k=0: fl(cx*T00)
                const float p0y = T10 * cx;
                const float ncx = __builtin_fmaf(T01, cy, p0x);   // k=1: fused accumulate
                const float ncy = __builtin_fmaf(T11, cy, p0y);
                const float u = ncx - 0.5f;
                const float v = ncy - 0.5f;
                const float xf = floorf(u), yf = floorf(v);
                const float xw = u - xf, yw = v - yf;
                int ix = (xf >= 2147483648.0f || xf < -2147483648.0f) ? (int)(-2147483647 - 1) : (int)xf;
                int iy = (yf >= 2147483648.0f || yf < -2147483648.0f) ? (int)(-2147483647 - 1) : (int)yf;
                const int x0 = ix & (RES - 1);
                const int x1 = (int)(((unsigned)ix + 1u) & (unsigned)(RES - 1));
                const int y0 = iy & (RES - 1);
                const int y1 = (int)(((unsigned)iy + 1u) & (unsigned)(RES - 1));
                float i00, i01, i10, i11;
                if constexpr (QUAD) {
                    const f16* pl = (const f16*)noise_v + (size_t)m * (256 * 256 * 4);
                    const int qx0 = x0 >> 1, sx0 = x0 & 1;
                    const int qx1 = x1 >> 1, sx1 = x1 & 1;
                    const int qy0 = y0 >> 1, sy0 = y0 & 1;
                    const int qy1 = y1 >> 1, sy1 = y1 & 1;
                    const uint2 qa = *(const uint2*)(pl + (qy0 * 256 + qx0) * 4);
                    const uint2 qb = *(const uint2*)(pl + (qy0 * 256 + qx1) * 4);
                    const uint2 qc = *(const uint2*)(pl + (qy1 * 256 + qx0) * 4);
                    const uint2 qd = *(const uint2*)(pl + (qy1 * 256 + qx1) * 4);
                    i00 = quad_tap(qa, sy0, sx0);
                    i01 = quad_tap(qb, sy0, sx1);
                    i10 = quad_tap(qc, sy1, sx0);
                    i11 = quad_tap(qd, sy1, sx1);
                } else {
                    const float* pl = (const float*)noise_v + (size_t)m * (RES * RES);
                    i00 = pl[y0 * RES + x0];
                    i01 = pl[y0 * RES + x1];
                    i10 = pl[y1 * RES + x0];
                    i11 = pl[y1 * RES + x1];
                }
                const float a0 = i00 + (i01 - i00) * xw;
                const float a1 = i10 + (i11 - i10) * xw;
                nvr[j][k] = a0 + (a1 - a0) * yw;
            }
        }
    }
    #pragma unroll
    for (int j = 0; j < 4; ++j) {
        #pragma unroll
        for (int k = 0; k < 4; ++k) {          // nv slot(m) = (m&7)*4 + (m>>3)
            const int m = mk[k];
            const int slot = (m & 7) * 4 + (m >> 3);
            nv_ws[(size_t)slot * Ntot + pb + 256 * j] = (f16)nvr[j][k];
        }
    }
}

// ---------------------------------------------------------------- mlp kernel
__global__ __launch_bounds__(256, 2)
void mlp_kernel(const f16* __restrict__ nv_ws,
                const f16* __restrict__ wf,
                const f16* __restrict__ waugf,
                const float* __restrict__ tw2,
                const float* __restrict__ tb2,
                float* __restrict__ out, const int Ntot)
{
    __shared__ f16 Wm[16384];           // 32 frags x 512 f16 = 32768 B, lane-linear
    __shared__ f16 Waug[4096];          //  8 frags x 512 f16 =  8192 B
    __shared__ f16 xa[PTS * XS];        // 35328 B
    __shared__ f16 xaug[PTS * AS];      //  4608 B
    __shared__ __align__(16) float tw2_sh[128];   // 512 B; total 81408 B

    const int t    = threadIdx.x;
    const int wave = t >> 6;
    const int lane = t & 63;
    const int q    = lane >> 4;
    const int l15  = lane & 15;
    const int pbase = blockIdx.x * PTS;
    const int pw    = wave * 32;        // wave-private point rows [pw, pw+32)
    const int p = t >> 1, h = t & 1;    // 2 threads per point (nv ownership)

    // ---------------- init ----------------
    if (t < 128) {
        tw2_sh[t] = tw2[t];
        xaug[t * AS + 8] = (f16)1.0f;          // bias lane
        #pragma unroll
        for (int c = 9; c < 16; ++c) xaug[t * AS + c] = (f16)0.0f;
    }
    const float tb2_0 = tb2[0];

    // nv gather: feat 16h+j = plane j*4+2h; coalesced scalar loads.
    f16x8 nva, nvb;
    {
        const int P = pbase + p;
        #pragma unroll
        for (int j = 0; j < 8; ++j) {
            nva[j] = nv_ws[(size_t)(j * 4 + 2 * h)     * Ntot + P];
            nvb[j] = nv_ws[(size_t)(j * 4 + 2 * h + 1) * Ntot + P];
        }
    }
    if (h == 0) *(f16x8*)&xaug[p * AS] = nva;   // layer-0 feats 0..7 (same-wave reader)

    // prologue: stage L0's Waug (Wm[0] unused — L0 main folded into c0 bias)
    {
        const f16x8 a0 = *(const f16x8*)&waugf[t * 8];
        const f16x8 a1 = *(const f16x8*)&waugf[(t + 256) * 8];
        *(f16x8*)&Waug[t * 8]         = a0;
        *(f16x8*)&Waug[(t + 256) * 8] = a1;
    }
    __syncthreads();   // init + L0 aug rows + L0 Waug visible to all waves

    // ---------------- 5 MFMA layers (L0 = aug-only) ----------------
    f32x4 acc[2][8];
    f16x8 wreg[8], areg[2];             // T14: next-layer weights in flight
    #pragma unroll 1
    for (int L = 0; L < 5; ++L) {
        if (L < 4) {   // issue L+1 weight loads NOW; latency hides under compute
            const f16* wsrc = wf + (L + 1) * 16384;
            #pragma unroll
            for (int i = 0; i < 8; ++i)
                wreg[i] = *(const f16x8*)&wsrc[(t + i * 256) * 8];
            const f16* asrc = waugf + (L + 1) * 4096;
            areg[0] = *(const f16x8*)&asrc[t * 8];
            areg[1] = *(const f16x8*)&asrc[(t + 256) * 8];
        }

        {
            const f32x4 z4 = {0.f, 0.f, 0.f, 0.f};
            #pragma unroll
            for (int i = 0; i < 2; ++i)
                #pragma unroll
                for (int mt = 0; mt < 8; ++mt) acc[i][mt] = z4;
        }
        const int pr0 = (pw + l15) * XS, pr1 = (pw + 16 + l15) * XS;
        if (L) {
            #pragma unroll
            for (int c = 0; c < 4; ++c) {   // main K=128
                const int kc = c * 32 + q * 8;
                const f16x8 xb0 = *(const f16x8*)&xa[pr0 + kc];
                const f16x8 xb1 = *(const f16x8*)&xa[pr1 + kc];
                #pragma unroll
                for (int mt = 0; mt < 8; ++mt) {
                    const f16x8 aw = *(const f16x8*)&Wm[((mt * 4 + c) * 64 + lane) * 8]; // conflict-free
                    acc[0][mt] = __builtin_amdgcn_mfma_f32_16x16x32_f16(aw, xb0, acc[0][mt], 0, 0, 0);
                    acc[1][mt] = __builtin_amdgcn_mfma_f32_16x16x32_f16(aw, xb1, acc[1][mt], 0, 0, 0);
                }
            }
        }
        {   // aug chunk: A-side fully stored (zeros for q>=2), B-side exec-masked
            f16x8 xb0 = {}, xb1 = {};
            if (q < 2) {
                xb0 = *(const f16x8*)&xaug[(pw + l15) * AS + q * 8];
                xb1 = *(const f16x8*)&xaug[(pw + 16 + l15) * AS + q * 8];
            }
            #pragma unroll
            for (int mt = 0; mt < 8; ++mt) {
                const f16x8 aw = *(const f16x8*)&Waug[(mt * 64 + lane) * 8];
                acc[0][mt] = __builtin_amdgcn_mfma_f32_16x16x32_f16(aw, xb0, acc[0][mt], 0, 0, 0);
                acc[1][mt] = __builtin_amdgcn_mfma_f32_16x16x32_f16(aw, xb1, acc[1][mt], 0, 0, 0);
            }
        }

        if (L < 4) {
            // epilogue: leaky-relu + pack; wave-private xa rows -> no barrier
            #pragma unroll
            for (int i = 0; i < 2; ++i) {
                const int pr = (pw + i * 16 + l15) * XS;
                #pragma unroll
                for (int mt = 0; mt < 8; ++mt) {
                    f16x4 hv;
                    #pragma unroll
                    for (int r = 0; r < 4; ++r) {
                        float v = acc[i][mt][r];
                        v = fmaxf(v, 0.01f * v);
                        hv[r] = (f16)v;
                    }
                    *(f16x4*)&xa[pr + mt * 16 + q * 4] = hv;
                }
            }
            if (L < 3) {   // next layer's nv into xaug (owning thread; same-wave reader)
                const int Ln = L + 1;
                if ((Ln >> 1) == h)
                    *(f16x8*)&xaug[p * AS] = (Ln & 1) ? nvb : nva;
            }
            __syncthreads();   // all waves done READING Wm/Waug for layer L
            {   // write the prefetched L+1 weights (loads long since landed)
                #pragma unroll
                for (int i = 0; i < 8; ++i)
                    *(f16x8*)&Wm[(t + i * 256) * 8] = wreg[i];
                *(f16x8*)&Waug[t * 8]         = areg[0];
                *(f16x8*)&Waug[(t + 256) * 8] = areg[1];
            }
            __syncthreads();   // staged weights visible for layer L+1
        } else {
            // head: out = tw2 . lrelu(h) + tb2; butterfly over quads
            #pragma unroll
            for (int i = 0; i < 2; ++i) {
                float s = 0.f;
                #pragma unroll
                for (int mt = 0; mt < 8; ++mt) {
                    const f32x4 w4 = *(const f32x4*)&tw2_sh[mt * 16 + q * 4];
                    #pragma unroll
                    for (int r = 0; r < 4; ++r) {
                        float v = acc[i][mt][r];
                        v = fmaxf(v, 0.01f * v);
                        s += w4[r] * v;
                    }
                }
                s += __shfl_xor(s, 16);
                s += __shfl_xor(s, 32);
                if (q == 0) out[pbase + pw + i * 16 + l15] = s + tb2_0;
            }
        }
    }
}

extern "C" void kernel_launch(void* const* d_in, const int* in_sizes, int n_in,
                              void* d_out, int out_size, void* d_ws, size_t ws_size,
                              hipStream_t stream) {
    const float* noise  = (const float*)d_in[0];
    const float* coords = (const float*)d_in[1];
    const float* trans  = (const float*)d_in[2];
    const float* ivec   = (const float*)d_in[3];
    const float* lw     = (const float*)d_in[4];
    const float* lb     = (const float*)d_in[5];
    const float* lnw    = (const float*)d_in[6];
    const float* tw1    = (const float*)d_in[7];
    const float* tb1    = (const float*)d_in[8];
    const float* tw2    = (const float*)d_in[9];
    const float* tb2    = (const float*)d_in[10];
    float* o            = (float*)d_out;

    const int N = in_sizes[1] / 2;                    // coords is [N,2]
    // ws layout: nv [32 planes][N] f16 (16 MiB) | wf | waug | quads (16 MiB)
    f16* nv    = (f16*)d_ws;
    const size_t NV = (size_t)N * 32;                 // f16 units
    f16* wfp   = nv + NV;
    f16* waugp = wfp + 5 * 16384;
    f16* qn    = waugp + 5 * 4096;
    const size_t need_full = (NV + 5 * 16384 + 5 * 4096
                              + (size_t)32 * 256 * 256 * 4) * sizeof(f16);

    if (ws_size >= need_full) {   // ws_size constant across calls -> graph-safe
        pack_all_k<<<8192 + 50, 256, 0, stream>>>(noise, qn, lw, lnw, lb, tw1, tb1,
                                                  ivec, wfp, waugp);
        sample_kernel<true><<<(N / 1024) * 8, 256, 0, stream>>>(qn, coords, trans, nv, N);
    } else {
        pack_w_k<<<50, 256, 0, stream>>>(lw, lnw, lb, tw1, tb1, ivec, wfp, waugp);
        sample_kernel<false><<<(N / 1024) * 8, 256, 0, stream>>>(noise, coords, trans, nv, N);
    }
    mlp_kernel<<<N / PTS, 256, 0, stream>>>(nv, wfp, waugp, tw2, tb2, o, N);
}

// Round 9
// 207.017 us; speedup vs baseline: 1.3773x; 1.0117x over previous
//
#include <hip/hip_runtime.h>

typedef _Float16 f16;
typedef f16 f16x4 __attribute__((ext_vector_type(4)));
typedef f16 f16x8 __attribute__((ext_vector_type(8)));
typedef float f32x4 __attribute__((ext_vector_type(4)));

#define RES 512
#define PTS 128     // mlp: points per block (4 waves x 32 pts)
#define XS  136     // f16 stride: 272B row = 17 quads -> 16B-provable alignment,
                    // quad-group (l15+q)%8 uniform -> b128 conflict-free
#define AS  16      // 32B row, 16B-aligned; aug b128 uniform over quad-groups

// R19: XS/AS alignment revert + zero-init peel. R18 evidence: conflicts went
// UP with XS 136->138 (3.96M->4.52M) — refutes R13's 8-way xb-conflict theory.
// Quad-granularity analysis: XS=136 b128 reads are phase-minimal (uniform 8
// lanes/quad-group). XS=138's real effect: 276B row stride is only 4B-aligned
// -> compiler can't prove 16B for f16x8 xa reads / f16x4 writes -> split LDS
// ops + extra addr VALU == the 37% VALUBusy. 136/16 restore provable 16B/8B
// alignment. Also: acc zero-init (64 writes x 4 layers/wave) replaced by
// zero-C on the c==0 MFMA (compile-time under unroll); only L0 zeroes.
// Numerics byte-identical to R18 (passed, 209.4us). Sample/pack untouched.

// ---------------------------------------------------------------- pack kernels
__device__ __forceinline__
void pack_w_body(int g, const float* __restrict__ lw, const float* __restrict__ lnw,
                 const float* __restrict__ lb, const float* __restrict__ tw1,
                 const float* __restrict__ tb1, const float* __restrict__ ivec,
                 f16* __restrict__ wf, f16* __restrict__ waugf) {
    if (g < 10240) {            // Wm fragments: 5 layers x 32 frags x 64 lanes
        const int L = g >> 11, r = g & 2047;
        const int lane = r & 63, frag = r >> 6;
        const int q = lane >> 4, l15 = lane & 15;
        const int mt = frag >> 2, c = frag & 3;
        const float* src = ((L < 4) ? (lw + L * 16384) : tw1)
                           + (mt * 16 + l15) * 128 + c * 32 + q * 8;
        f16x8 h;
        #pragma unroll
        for (int j = 0; j < 8; ++j) h[j] = (f16)src[j];
        *(f16x8*)(wf + (size_t)g * 8) = h;
    } else {                    // Waug fragments: 5 layers x 8 frags x 64 lanes
        const int ga = g - 10240;            // < 2560
        const int L = ga >> 9, r = ga & 511;
        const int lane = r & 63, mt = r >> 6;
        const int q = lane >> 4, l15 = lane & 15;
        const int row = mt * 16 + l15;
        f16x8 h = {};
        if (q == 0 && L < 4) {               // k=0..7: lnw slice
            const float* src = lnw + L * 1024 + row * 8;
            #pragma unroll
            for (int j = 0; j < 8; ++j) h[j] = (f16)src[j];
        }
        if (q == 1) {                        // k=8: bias (L0: + lw0@ivec const)
            if (L == 0) {
                float s = lb[row];
                const float4* w4 = (const float4*)(lw + row * 128);
                const float4* v4 = (const float4*)ivec;
                #pragma unroll 8
                for (int k = 0; k < 32; ++k) {
                    const float4 w = w4[k], v = v4[k];
                    s += w.x * v.x + w.y * v.y + w.z * v.z + w.w * v.w;
                }
                h[0] = (f16)s;
            } else {
                h[0] = (f16)((L < 4) ? lb[L * 128 + row] : tb1[row]);
            }
        }
        *(f16x8*)(waugf + (size_t)ga * 8) = h;
    }
}

__global__ __launch_bounds__(256)
void pack_all_k(const float* __restrict__ n, f16* __restrict__ q,
                const float* __restrict__ lw,  const float* __restrict__ lnw,
                const float* __restrict__ lb,  const float* __restrict__ tw1,
                const float* __restrict__ tb1, const float* __restrict__ ivec,
                f16* __restrict__ wf, f16* __restrict__ waugf) {
    const int b = blockIdx.x;
    if (b < 8192) {   // quad packing: one thread per 2x2 texel quad
        const int idx = b * 256 + threadIdx.x;
        const int qx = idx & 255, rest = idx >> 8;
        const int qy = rest & 255, m = rest >> 8;
        const float* src = n + ((size_t)m * 512 + 2 * qy) * 512 + 2 * qx;
        const float2 r0 = *(const float2*)(src);
        const float2 r1 = *(const float2*)(src + 512);
        f16x4 o; o[0]=(f16)r0.x; o[1]=(f16)r0.y; o[2]=(f16)r1.x; o[3]=(f16)r1.y;
        *(f16x4*)(q + (size_t)idx * 4) = o;
    } else {
        pack_w_body((b - 8192) * 256 + threadIdx.x, lw, lnw, lb, tw1, tb1, ivec, wf, waugf);
    }
}

__global__ __launch_bounds__(256)
void pack_w_k(const float* __restrict__ lw,  const float* __restrict__ lnw,
              const float* __restrict__ lb,  const float* __restrict__ tw1,
              const float* __restrict__ tb1, const float* __restrict__ ivec,
              f16* __restrict__ wf, f16* __restrict__ waugf) {
    pack_w_body(blockIdx.x * 256 + threadIdx.x, lw, lnw, lb, tw1, tb1, ivec, wf, waugf);
}

// ---------------------------------------------------------------- sample kernel
__device__ __forceinline__ float quad_tap(uint2 q, int sy, int sx) {
    unsigned w = sy ? q.y : q.x;          // row select within quad
    w >>= (sx << 4);                      // col select (low/high half)
    union { unsigned short u; f16 h; } cv; cv.u = (unsigned short)w;
    return (float)cv.h;
}

template <bool QUAD>
__global__ __launch_bounds__(256, 4)
void sample_kernel(const void* __restrict__ noise_v,
                   const float* __restrict__ coords,
                   const float* __restrict__ trans,
                   f16* __restrict__ nv_ws, const int Ntot)
{
    __shared__ float T_sh[128];
    const int t = threadIdx.x;
    if (t < 128) T_sh[t] = trans[t];
    __syncthreads();

    const int g = blockIdx.x & 7;                     // feature group -> XCD pin
    const int pb = (blockIdx.x >> 3) * 1024 + t;      // 4 points: pb + 256*j

    // cost-balanced plane sets (expensive planes m=9..31 split 3/..3/2)
    int mk[4];
    if (g < 7) { mk[0] = g; mk[1] = g + 9; mk[2] = g + 17; mk[3] = g + 25; }
    else       { mk[0] = 7; mk[1] = 8;     mk[2] = 16;     mk[3] = 24;     }

    float2 c[4];
    #pragma unroll
    for (int j = 0; j < 4; ++j)
        c[j] = *(const float2*)(coords + (pb + 256 * j) * 2);

    float nvr[4][4];
    {
        #pragma clang fp contract(off)
        #pragma unroll
        for (int j = 0; j < 4; ++j) {
            const float cx = c[j].x;
            const float cy = c[j].y;
            #pragma unroll
            for (int k = 0; k < 4; ++k) {
                const int m = mk[k];
                const float T00 = T_sh[m*4+0], T01 = T_sh[m*4+1];
                const float T10 = T_sh[m*4+2], T11 = T_sh[m*4+3];
                const float p0x = T00 * cx;                       // k=0: fl(cx*T00)
                const float p0y = T10 * cx;
                const float ncx = __builtin_fmaf(T01, cy, p0x);   // k=1: fused accumulate
                const float ncy = __builtin_fmaf(T11, cy, p0y);
                const float u = ncx - 0.5f;
                const float v = ncy - 0.5f;
                const float xf = floorf(u), yf = floorf(v);
                const float xw = u - xf, yw = v - yf;
                int ix = (xf >= 2147483648.0f || xf < -2147483648.0f) ? (int)(-2147483647 - 1) : (int)xf;
                int iy = (yf >= 2147483648.0f || yf < -2147483648.0f) ? (int)(-2147483647 - 1) : (int)yf;
                const int x0 = ix & (RES - 1);
                const int x1 = (int)(((unsigned)ix + 1u) & (unsigned)(RES - 1));
                const int y0 = iy & (RES - 1);
                const int y1 = (int)(((unsigned)iy + 1u) & (unsigned)(RES - 1));
                float i00, i01, i10, i11;
                if constexpr (QUAD) {
                    const f16* pl = (const f16*)noise_v + (size_t)m * (256 * 256 * 4);
                    const int qx0 = x0 >> 1, sx0 = x0 & 1;
                    const int qx1 = x1 >> 1, sx1 = x1 & 1;
                    const int qy0 = y0 >> 1, sy0 = y0 & 1;
                    const int qy1 = y1 >> 1, sy1 = y1 & 1;
                    const uint2 qa = *(const uint2*)(pl + (qy0 * 256 + qx0) * 4);
                    const uint2 qb = *(const uint2*)(pl + (qy0 * 256 + qx1) * 4);
                    const uint2 qc = *(const uint2*)(pl + (qy1 * 256 + qx0) * 4);
                    const uint2 qd = *(const uint2*)(pl + (qy1 * 256 + qx1) * 4);
                    i00 = quad_tap(qa, sy0, sx0);
                    i01 = quad_tap(qb, sy0, sx1);
                    i10 = quad_tap(qc, sy1, sx0);
                    i11 = quad_tap(qd, sy1, sx1);
                } else {
                    const float* pl = (const float*)noise_v + (size_t)m * (RES * RES);
                    i00 = pl[y0 * RES + x0];
                    i01 = pl[y0 * RES + x1];
                    i10 = pl[y1 * RES + x0];
                    i11 = pl[y1 * RES + x1];
                }
                const float a0 = i00 + (i01 - i00) * xw;
                const float a1 = i10 + (i11 - i10) * xw;
                nvr[j][k] = a0 + (a1 - a0) * yw;
            }
        }
    }
    #pragma unroll
    for (int j = 0; j < 4; ++j) {
        #pragma unroll
        for (int k = 0; k < 4; ++k) {          // nv slot(m) = (m&7)*4 + (m>>3)
            const int m = mk[k];
            const int slot = (m & 7) * 4 + (m >> 3);
            nv_ws[(size_t)slot * Ntot + pb + 256 * j] = (f16)nvr[j][k];
        }
    }
}

// ---------------------------------------------------------------- mlp kernel
__global__ __launch_bounds__(256, 2)
void mlp_kernel(const f16* __restrict__ nv_ws,
                const f16* __restrict__ wf,
                const f16* __restrict__ waugf,
                const float* __restrict__ tw2,
                const float* __restrict__ tb2,
                float* __restrict__ out, const int Ntot)
{
    __shared__ f16 Wm[16384];           // 32 frags x 512 f16 = 32768 B, lane-linear
    __shared__ f16 Waug[4096];          //  8 frags x 512 f16 =  8192 B
    __shared__ f16 xa[PTS * XS];        // 34816 B
    __shared__ f16 xaug[PTS * AS];      //  4096 B
    __shared__ __align__(16) float tw2_sh[128];   // 512 B; total 80384 B

    const int t    = threadIdx.x;
    const int wave = t >> 6;
    const int lane = t & 63;
    const int q    = lane >> 4;
    const int l15  = lane & 15;
    const int pbase = blockIdx.x * PTS;
    const int pw    = wave * 32;        // wave-private point rows [pw, pw+32)
    const int p = t >> 1, h = t & 1;    // 2 threads per point (nv ownership)

    // ---------------- init ----------------
    if (t < 128) {
        tw2_sh[t] = tw2[t];
        xaug[t * AS + 8] = (f16)1.0f;          // bias lane
        #pragma unroll
        for (int c = 9; c < 16; ++c) xaug[t * AS + c] = (f16)0.0f;
    }
    const float tb2_0 = tb2[0];

    // nv gather: feat 16h+j = plane j*4+2h; coalesced scalar loads.
    f16x8 nva, nvb;
    {
        const int P = pbase + p;
        #pragma unroll
        for (int j = 0; j < 8; ++j) {
            nva[j] = nv_ws[(size_t)(j * 4 + 2 * h)     * Ntot + P];
            nvb[j] = nv_ws[(size_t)(j * 4 + 2 * h + 1) * Ntot + P];
        }
    }
    if (h == 0) *(f16x8*)&xaug[p * AS] = nva;   // layer-0 feats 0..7 (same-wave reader)

    // prologue: stage L0's Waug (Wm[0] unused — L0 main folded into c0 bias)
    {
        const f16x8 a0 = *(const f16x8*)&waugf[t * 8];
        const f16x8 a1 = *(const f16x8*)&waugf[(t + 256) * 8];
        *(f16x8*)&Waug[t * 8]         = a0;
        *(f16x8*)&Waug[(t + 256) * 8] = a1;
    }
    __syncthreads();   // init + L0 aug rows + L0 Waug visible to all waves

    // ---------------- 5 MFMA layers (L0 = aug-only) ----------------
    const f32x4 z4 = {0.f, 0.f, 0.f, 0.f};
    f32x4 acc[2][8];
    f16x8 wreg[8], areg[2];             // T14: next-layer weights in flight
    #pragma unroll 1
    for (int L = 0; L < 5; ++L) {
        if (L < 4) {   // issue L+1 weight loads NOW; latency hides under compute
            const f16* wsrc = wf + (L + 1) * 16384;
            #pragma unroll
            for (int i = 0; i < 8; ++i)
                wreg[i] = *(const f16x8*)&wsrc[(t + i * 256) * 8];
            const f16* asrc = waugf + (L + 1) * 4096;
            areg[0] = *(const f16x8*)&asrc[t * 8];
            areg[1] = *(const f16x8*)&asrc[(t + 256) * 8];
        }

        if (L == 0) {   // only L0 needs explicit zero (aug accumulates into it);
            #pragma unroll // L>=1 uses zero-C on the c==0 MFMA below
            for (int i = 0; i < 2; ++i)
                #pragma unroll
                for (int mt = 0; mt < 8; ++mt) acc[i][mt] = z4;
        }
        const int pr0 = (pw + l15) * XS, pr1 = (pw + 16 + l15) * XS;
        if (L) {
            #pragma unroll
            for (int c = 0; c < 4; ++c) {   // main K=128
                const int kc = c * 32 + q * 8;
                const f16x8 xb0 = *(const f16x8*)&xa[pr0 + kc];
                const f16x8 xb1 = *(const f16x8*)&xa[pr1 + kc];
                #pragma unroll
                for (int mt = 0; mt < 8; ++mt) {
                    const f16x8 aw = *(const f16x8*)&Wm[((mt * 4 + c) * 64 + lane) * 8]; // conflict-free
                    const f32x4 c0 = (c == 0) ? z4 : acc[0][mt];   // compile-time select
                    const f32x4 c1 = (c == 0) ? z4 : acc[1][mt];
                    acc[0][mt] = __builtin_amdgcn_mfma_f32_16x16x32_f16(aw, xb0, c0, 0, 0, 0);
                    acc[1][mt] = __builtin_amdgcn_mfma_f32_16x16x32_f16(aw, xb1, c1, 0, 0, 0);
                }
            }
        }
        {   // aug chunk: A-side fully stored (zeros for q>=2), B-side exec-masked
            f16x8 xb0 = {}, xb1 = {};
            if (q < 2) {
                xb0 = *(const f16x8*)&xaug[(pw + l15) * AS + q * 8];
                xb1 = *(const f16x8*)&xaug[(pw + 16 + l15) * AS + q * 8];
            }
            #pragma unroll
            for (int mt = 0; mt < 8; ++mt) {
                const f16x8 aw = *(const f16x8*)&Waug[(mt * 64 + lane) * 8];
                acc[0][mt] = __builtin_amdgcn_mfma_f32_16x16x32_f16(aw, xb0, acc[0][mt], 0, 0, 0);
                acc[1][mt] = __builtin_amdgcn_mfma_f32_16x16x32_f16(aw, xb1, acc[1][mt], 0, 0, 0);
            }
        }

        if (L < 4) {
            // epilogue: leaky-relu + pack; wave-private xa rows -> no barrier
            #pragma unroll
            for (int i = 0; i < 2; ++i) {
                const int pr = (pw + i * 16 + l15) * XS;
                #pragma unroll
                for (int mt = 0; mt < 8; ++mt) {
                    f16x4 hv;
                    #pragma unroll
                    for (int r = 0; r < 4; ++r) {
                        float v = acc[i][mt][r];
                        v = fmaxf(v, 0.01f * v);
                        hv[r] = (f16)v;
                    }
                    *(f16x4*)&xa[pr + mt * 16 + q * 4] = hv;
                }
            }
            if (L < 3) {   // next layer's nv into xaug (owning thread; same-wave reader)
                const int Ln = L + 1;
                if ((Ln >> 1) == h)
                    *(f16x8*)&xaug[p * AS] = (Ln & 1) ? nvb : nva;
            }
            __syncthreads();   // all waves done READING Wm/Waug for layer L
            {   // write the prefetched L+1 weights (loads long since landed)
                #pragma unroll
                for (int i = 0; i < 8; ++i)
                    *(f16x8*)&Wm[(t + i * 256) * 8] = wreg[i];
                *(f16x8*)&Waug[t * 8]         = areg[0];
                *(f16x8*)&Waug[(t + 256) * 8] = areg[1];
            }
            __syncthreads();   // staged weights visible for layer L+1
        } else {
            // head: out = tw2 . lrelu(h) + tb2; butterfly over quads
            #pragma unroll
            for (int i = 0; i < 2; ++i) {
                float s = 0.f;
                #pragma unroll
                for (int mt = 0; mt < 8; ++mt) {
                    const f32x4 w4 = *(const f32x4*)&tw2_sh[mt * 16 + q * 4];
                    #pragma unroll
                    for (int r = 0; r < 4; ++r) {
                        float v = acc[i][mt][r];
                        v = fmaxf(v, 0.01f * v);
                        s += w4[r] * v;
                    }
                }
                s += __shfl_xor(s, 16);
                s += __shfl_xor(s, 32);
                if (q == 0) out[pbase + pw + i * 16 + l15] = s + tb2_0;
            }
        }
    }
}

extern "C" void kernel_launch(void* const* d_in, const int* in_sizes, int n_in,
                              void* d_out, int out_size, void* d_ws, size_t ws_size,
                              hipStream_t stream) {
    const float* noise  = (const float*)d_in[0];
    const float* coords = (const float*)d_in[1];
    const float* trans  = (const float*)d_in[2];
    const float* ivec   = (const float*)d_in[3];
    const float* lw     = (const float*)d_in[4];
    const float* lb     = (const float*)d_in[5];
    const float* lnw    = (const float*)d_in[6];
    const float* tw1    = (const float*)d_in[7];
    const float* tb1    = (const float*)d_in[8];
    const float* tw2    = (const float*)d_in[9];
    const float* tb2    = (const float*)d_in[10];
    float* o            = (float*)d_out;

    const int N = in_sizes[1] / 2;                    // coords is [N,2]
    // ws layout: nv [32 planes][N] f16 (16 MiB) | wf | waug | quads (16 MiB)
    f16* nv    = (f16*)d_ws;
    const size_t NV = (size_t)N * 32;                 // f16 units
    f16* wfp   = nv + NV;
    f16* waugp = wfp + 5 * 16384;
    f16* qn    = waugp + 5 * 4096;
    const size_t need_full = (NV + 5 * 16384 + 5 * 4096
                              + (size_t)32 * 256 * 256 * 4) * sizeof(f16);

    if (ws_size >= need_full) {   // ws_size constant across calls -> graph-safe
        pack_all_k<<<8192 + 50, 256, 0, stream>>>(noise, qn, lw, lnw, lb, tw1, tb1,
                                                  ivec, wfp, waugp);
        sample_kernel<true><<<(N / 1024) * 8, 256, 0, stream>>>(qn, coords, trans, nv, N);
    } else {
        pack_w_k<<<50, 256, 0, stream>>>(lw, lnw, lb, tw1, tb1, ivec, wfp, waugp);
        sample_kernel<false><<<(N / 1024) * 8, 256, 0, stream>>>(noise, coords, trans, nv, N);
    }
    mlp_kernel<<<N / PTS, 256, 0, stream>>>(nv, wfp, waugp, tw2, tb2, o, N);
}

// Round 10
// 205.702 us; speedup vs baseline: 1.3861x; 1.0064x over previous
//
#include <hip/hip_runtime.h>

typedef _Float16 f16;
typedef f16 f16x4 __attribute__((ext_vector_type(4)));
typedef f16 f16x8 __attribute__((ext_vector_type(8)));
typedef float f32x4 __attribute__((ext_vector_type(4)));

#define RES 512
#define PTS 128     // mlp: points per block
#define XS  136     // f16 stride: 272B row, 16B-aligned, b128 phase-minimal
#define AS  16      // 32B row, 16B-aligned

// R20: 2x2 wave-quadrant mlp. R19 showed conflicts drop (4.5M->3.2M) without
// dur gain -> residual is LDS-pipe volume: per CU, b128 reads ~31us + writes
// ~9us vs MFMA 22us, VALU 21us; aw weight reads (40/50 per layer/wave) are
// duplicated because every wave reads ALL of Wm (pt-slice). New: wave (wi,wj)
// owns points [wi*64,+64) x features [wj*64,+64): per c-chunk 4 aw + 4 xb
// feed 16 MFMAs -> reads/layer 50->40 (-20%), acc stays 64 regs, MFMA count
// unchanged. xa deps cross-wave now but already covered by the existing 2
// barriers/layer (epilogue writes before barrier1, reads after barrier2).
// Head: 2-partial combine via pp[2][128] (1KB; LDS 81408B = 2 blocks/CU,
// same as R17 measured). Per-element math identical. Sample/pack untouched.

// ---------------------------------------------------------------- pack kernels
__device__ __forceinline__
void pack_w_body(int g, const float* __restrict__ lw, const float* __restrict__ lnw,
                 const float* __restrict__ lb, const float* __restrict__ tw1,
                 const float* __restrict__ tb1, const float* __restrict__ ivec,
                 f16* __restrict__ wf, f16* __restrict__ waugf) {
    if (g < 10240) {            // Wm fragments: 5 layers x 32 frags x 64 lanes
        const int L = g >> 11, r = g & 2047;
        const int lane = r & 63, frag = r >> 6;
        const int q = lane >> 4, l15 = lane & 15;
        const int mt = frag >> 2, c = frag & 3;
        const float* src = ((L < 4) ? (lw + L * 16384) : tw1)
                           + (mt * 16 + l15) * 128 + c * 32 + q * 8;
        f16x8 h;
        #pragma unroll
        for (int j = 0; j < 8; ++j) h[j] = (f16)src[j];
        *(f16x8*)(wf + (size_t)g * 8) = h;
    } else {                    // Waug fragments: 5 layers x 8 frags x 64 lanes
        const int ga = g - 10240;            // < 2560
        const int L = ga >> 9, r = ga & 511;
        const int lane = r & 63, mt = r >> 6;
        const int q = lane >> 4, l15 = lane & 15;
        const int row = mt * 16 + l15;
        f16x8 h = {};
        if (q == 0 && L < 4) {               // k=0..7: lnw slice
            const float* src = lnw + L * 1024 + row * 8;
            #pragma unroll
            for (int j = 0; j < 8; ++j) h[j] = (f16)src[j];
        }
        if (q == 1) {                        // k=8: bias (L0: + lw0@ivec const)
            if (L == 0) {
                float s = lb[row];
                const float4* w4 = (const float4*)(lw + row * 128);
                const float4* v4 = (const float4*)ivec;
                #pragma unroll 8
                for (int k = 0; k < 32; ++k) {
                    const float4 w = w4[k], v = v4[k];
                    s += w.x * v.x + w.y * v.y + w.z * v.z + w.w * v.w;
                }
                h[0] = (f16)s;
            } else {
                h[0] = (f16)((L < 4) ? lb[L * 128 + row] : tb1[row]);
            }
        }
        *(f16x8*)(waugf + (size_t)ga * 8) = h;
    }
}

__global__ __launch_bounds__(256)
void pack_all_k(const float* __restrict__ n, f16* __restrict__ q,
                const float* __restrict__ lw,  const float* __restrict__ lnw,
                const float* __restrict__ lb,  const float* __restrict__ tw1,
                const float* __restrict__ tb1, const float* __restrict__ ivec,
                f16* __restrict__ wf, f16* __restrict__ waugf) {
    const int b = blockIdx.x;
    if (b < 8192) {   // quad packing: one thread per 2x2 texel quad
        const int idx = b * 256 + threadIdx.x;
        const int qx = idx & 255, rest = idx >> 8;
        const int qy = rest & 255, m = rest >> 8;
        const float* src = n + ((size_t)m * 512 + 2 * qy) * 512 + 2 * qx;
        const float2 r0 = *(const float2*)(src);
        const float2 r1 = *(const float2*)(src + 512);
        f16x4 o; o[0]=(f16)r0.x; o[1]=(f16)r0.y; o[2]=(f16)r1.x; o[3]=(f16)r1.y;
        *(f16x4*)(q + (size_t)idx * 4) = o;
    } else {
        pack_w_body((b - 8192) * 256 + threadIdx.x, lw, lnw, lb, tw1, tb1, ivec, wf, waugf);
    }
}

__global__ __launch_bounds__(256)
void pack_w_k(const float* __restrict__ lw,  const float* __restrict__ lnw,
              const float* __restrict__ lb,  const float* __restrict__ tw1,
              const float* __restrict__ tb1, const float* __restrict__ ivec,
              f16* __restrict__ wf, f16* __restrict__ waugf) {
    pack_w_body(blockIdx.x * 256 + threadIdx.x, lw, lnw, lb, tw1, tb1, ivec, wf, waugf);
}

// ---------------------------------------------------------------- sample kernel
__device__ __forceinline__ float quad_tap(uint2 q, int sy, int sx) {
    unsigned w = sy ? q.y : q.x;          // row select within quad
    w >>= (sx << 4);                      // col select (low/high half)
    union { unsigned short u; f16 h; } cv; cv.u = (unsigned short)w;
    return (float)cv.h;
}

template <bool QUAD>
__global__ __launch_bounds__(256, 4)
void sample_kernel(const void* __restrict__ noise_v,
                   const float* __restrict__ coords,
                   const float* __restrict__ trans,
                   f16* __restrict__ nv_ws, const int Ntot)
{
    __shared__ float T_sh[128];
    const int t = threadIdx.x;
    if (t < 128) T_sh[t] = trans[t];
    __syncthreads();

    const int g = blockIdx.x & 7;                     // feature group -> XCD pin
    const int pb = (blockIdx.x >> 3) * 1024 + t;      // 4 points: pb + 256*j

    // cost-balanced plane sets (expensive planes m=9..31 split 3/..3/2)
    int mk[4];
    if (g < 7) { mk[0] = g; mk[1] = g + 9; mk[2] = g + 17; mk[3] = g + 25; }
    else       { mk[0] = 7; mk[1] = 8;     mk[2] = 16;     mk[3] = 24;     }

    float2 c[4];
    #pragma unroll
    for (int j = 0; j < 4; ++j)
        c[j] = *(const float2*)(coords + (pb + 256 * j) * 2);

    float nvr[4][4];
    {
        #pragma clang fp contract(off)
        #pragma unroll
        for (int j = 0; j < 4; ++j) {
            const float cx = c[j].x;
            const float cy = c[j].y;
            #pragma unroll
            for (int k = 0; k < 4; ++k) {
                const int m = mk[k];
                const float T00 = T_sh[m*4+0], T01 = T_sh[m*4+1];
                const float T10 = T_sh[m*4+2], T11 = T_sh[m*4+3];
                const float p0x = T00 * cx;                       // k=0: fl(cx*T00)
                const float p0y = T10 * cx;
                const float ncx = __builtin_fmaf(T01, cy, p0x);   // k=1: fused accumulate
                const float ncy = __builtin_fmaf(T11, cy, p0y);
                const float u = ncx - 0.5f;
                const float v = ncy - 0.5f;
                const float xf = floorf(u), yf = floorf(v);
                const float xw = u - xf, yw = v - yf;
                int ix = (xf >= 2147483648.0f || xf < -2147483648.0f) ? (int)(-2147483647 - 1) : (int)xf;
                int iy = (yf >= 2147483648.0f || yf < -2147483648.0f) ? (int)(-2147483647 - 1) : (int)yf;
                const int x0 = ix & (RES - 1);
                const int x1 = (int)(((unsigned)ix + 1u) & (unsigned)(RES - 1));
                const int y0 = iy & (RES - 1);
                const int y1 = (int)(((unsigned)iy + 1u) & (unsigned)(RES - 1));
                float i00, i01, i10, i11;
                if constexpr (QUAD) {
                    const f16* pl = (const f16*)noise_v + (size_t)m * (256 * 256 * 4);
                    const int qx0 = x0 >> 1, sx0 = x0 & 1;
                    const int qx1 = x1 >> 1, sx1 = x1 & 1;
                    const int qy0 = y0 >> 1, sy0 = y0 & 1;
                    const int qy1 = y1 >> 1, sy1 = y1 & 1;
                    const uint2 qa = *(const uint2*)(pl + (qy0 * 256 + qx0) * 4);
                    const uint2 qb = *(const uint2*)(pl + (qy0 * 256 + qx1) * 4);
                    const uint2 qc = *(const uint2*)(pl + (qy1 * 256 + qx0) * 4);
                    const uint2 qd = *(const uint2*)(pl + (qy1 * 256 + qx1) * 4);
                    i00 = quad_tap(qa, sy0, sx0);
                    i01 = quad_tap(qb, sy0, sx1);
                    i10 = quad_tap(qc, sy1, sx0);
                    i11 = quad_tap(qd, sy1, sx1);
                } else {
                    const float* pl = (const float*)noise_v + (size_t)m * (RES * RES);
                    i00 = pl[y0 * RES + x0];
                    i01 = pl[y0 * RES + x1];
                    i10 = pl[y1 * RES + x0];
                    i11 = pl[y1 * RES + x1];
                }
                const float a0 = i00 + (i01 - i00) * xw;
                const float a1 = i10 + (i11 - i10) * xw;
                nvr[j][k] = a0 + (a1 - a0) * yw;
            }
        }
    }
    #pragma unroll
    for (int j = 0; j < 4; ++j) {
        #pragma unroll
        for (int k = 0; k < 4; ++k) {          // nv slot(m) = (m&7)*4 + (m>>3)
            const int m = mk[k];
            const int slot = (m & 7) * 4 + (m >> 3);
            nv_ws[(size_t)slot * Ntot + pb + 256 * j] = (f16)nvr[j][k];
        }
    }
}

// ---------------------------------------------------------------- mlp kernel
__global__ __launch_bounds__(256, 2)
void mlp_kernel(const f16* __restrict__ nv_ws,
                const f16* __restrict__ wf,
                const f16* __restrict__ waugf,
                const float* __restrict__ tw2,
                const float* __restrict__ tb2,
                float* __restrict__ out, const int Ntot)
{
    __shared__ f16 Wm[16384];           // 32 frags x 512 f16 = 32768 B, lane-linear
    __shared__ f16 Waug[4096];          //  8 frags x 512 f16 =  8192 B
    __shared__ f16 xa[PTS * XS];        // 34816 B
    __shared__ f16 xaug[PTS * AS];      //  4096 B
    __shared__ __align__(16) float tw2_sh[128];   // 512 B
    __shared__ float pp[2][PTS];        // 1024 B head partials; total 81408 B

    const int t    = threadIdx.x;
    const int wave = t >> 6;
    const int lane = t & 63;
    const int q    = lane >> 4;
    const int l15  = lane & 15;
    const int wi   = wave >> 1;         // point-half  [wi*64, +64)
    const int wj   = wave & 1;          // feature-half [wj*64, +64)
    const int pbase = blockIdx.x * PTS;
    const int p = t >> 1, h = t & 1;    // 2 threads per point (nv ownership)

    // ---------------- init ----------------
    if (t < 128) {
        tw2_sh[t] = tw2[t];
        xaug[t * AS + 8] = (f16)1.0f;          // bias lane
        #pragma unroll
        for (int c = 9; c < 16; ++c) xaug[t * AS + c] = (f16)0.0f;
    }
    const float tb2_0 = tb2[0];

    // nv gather: feat 16h+j = plane j*4+2h; coalesced scalar loads.
    f16x8 nva, nvb;
    {
        const int P = pbase + p;
        #pragma unroll
        for (int j = 0; j < 8; ++j) {
            nva[j] = nv_ws[(size_t)(j * 4 + 2 * h)     * Ntot + P];
            nvb[j] = nv_ws[(size_t)(j * 4 + 2 * h + 1) * Ntot + P];
        }
    }
    if (h == 0) *(f16x8*)&xaug[p * AS] = nva;   // layer-0 feats 0..7

    // prologue: stage L0's Waug (Wm[0] unused — L0 main folded into c0 bias)
    {
        const f16x8 a0 = *(const f16x8*)&waugf[t * 8];
        const f16x8 a1 = *(const f16x8*)&waugf[(t + 256) * 8];
        *(f16x8*)&Waug[t * 8]         = a0;
        *(f16x8*)&Waug[(t + 256) * 8] = a1;
    }
    __syncthreads();   // init + L0 aug rows + L0 Waug visible to all waves

    // ---------------- 5 MFMA layers (L0 = aug-only) ----------------
    const f32x4 z4 = {0.f, 0.f, 0.f, 0.f};
    f32x4 acc[4][4];                    // [pt-group][mt-local]
    f16x8 wreg[8], areg[2];             // T14: next-layer weights in flight
    #pragma unroll 1
    for (int L = 0; L < 5; ++L) {
        if (L < 4) {   // issue L+1 weight loads NOW; latency hides under compute
            const f16* wsrc = wf + (L + 1) * 16384;
            #pragma unroll
            for (int i = 0; i < 8; ++i)
                wreg[i] = *(const f16x8*)&wsrc[(t + i * 256) * 8];
            const f16* asrc = waugf + (L + 1) * 4096;
            areg[0] = *(const f16x8*)&asrc[t * 8];
            areg[1] = *(const f16x8*)&asrc[(t + 256) * 8];
        }

        if (L == 0) {   // only L0 needs explicit zero (aug accumulates into it)
            #pragma unroll
            for (int pg = 0; pg < 4; ++pg)
                #pragma unroll
                for (int mtl = 0; mtl < 4; ++mtl) acc[pg][mtl] = z4;
        }
        if (L) {
            #pragma unroll
            for (int c = 0; c < 4; ++c) {   // main K=128
                const int kc = c * 32 + q * 8;
                f16x8 xb[4];
                #pragma unroll
                for (int pg = 0; pg < 4; ++pg)
                    xb[pg] = *(const f16x8*)&xa[(wi * 64 + pg * 16 + l15) * XS + kc];
                #pragma unroll
                for (int mtl = 0; mtl < 4; ++mtl) {
                    const f16x8 aw = *(const f16x8*)
                        &Wm[(((wj * 4 + mtl) * 4 + c) * 64 + lane) * 8]; // lane-linear
                    #pragma unroll
                    for (int pg = 0; pg < 4; ++pg) {
                        const f32x4 ci = (c == 0) ? z4 : acc[pg][mtl];  // compile-time
                        acc[pg][mtl] = __builtin_amdgcn_mfma_f32_16x16x32_f16(aw, xb[pg], ci, 0, 0, 0);
                    }
                }
            }
        }
        {   // aug chunk: A-side fully stored (zeros for q>=2), B-side exec-masked
            f16x8 xb[4] = {};
            if (q < 2) {
                #pragma unroll
                for (int pg = 0; pg < 4; ++pg)
                    xb[pg] = *(const f16x8*)&xaug[(wi * 64 + pg * 16 + l15) * AS + q * 8];
            }
            #pragma unroll
            for (int mtl = 0; mtl < 4; ++mtl) {
                const f16x8 aw = *(const f16x8*)&Waug[((wj * 4 + mtl) * 64 + lane) * 8];
                #pragma unroll
                for (int pg = 0; pg < 4; ++pg)
                    acc[pg][mtl] = __builtin_amdgcn_mfma_f32_16x16x32_f16(aw, xb[pg], acc[pg][mtl], 0, 0, 0);
            }
        }

        if (L < 4) {
            // epilogue: leaky-relu + pack into this wave's (pt,feat) quadrant
            #pragma unroll
            for (int pg = 0; pg < 4; ++pg) {
                const int pr = (wi * 64 + pg * 16 + l15) * XS;
                #pragma unroll
                for (int mtl = 0; mtl < 4; ++mtl) {
                    f16x4 hv;
                    #pragma unroll
                    for (int r = 0; r < 4; ++r) {
                        float v = acc[pg][mtl][r];
                        v = fmaxf(v, 0.01f * v);
                        hv[r] = (f16)v;
                    }
                    *(f16x4*)&xa[pr + wj * 64 + mtl * 16 + q * 4] = hv;
                }
            }
            if (L < 3) {   // next layer's nv into xaug (owning thread)
                const int Ln = L + 1;
                if ((Ln >> 1) == h)
                    *(f16x8*)&xaug[p * AS] = (Ln & 1) ? nvb : nva;
            }
            __syncthreads();   // xa/xaug writes done + all waves done reading Wm/Waug
            {   // write the prefetched L+1 weights (loads long since landed)
                #pragma unroll
                for (int i = 0; i < 8; ++i)
                    *(f16x8*)&Wm[(t + i * 256) * 8] = wreg[i];
                *(f16x8*)&Waug[t * 8]         = areg[0];
                *(f16x8*)&Waug[(t + 256) * 8] = areg[1];
            }
            __syncthreads();   // staged weights + xa visible for layer L+1
        } else {
            // head: partial dot over this wave's 64 features; combine via pp
            #pragma unroll
            for (int pg = 0; pg < 4; ++pg) {
                float s = 0.f;
                #pragma unroll
                for (int mtl = 0; mtl < 4; ++mtl) {
                    const f32x4 w4 = *(const f32x4*)&tw2_sh[wj * 64 + mtl * 16 + q * 4];
                    #pragma unroll
                    for (int r = 0; r < 4; ++r) {
                        float v = acc[pg][mtl][r];
                        v = fmaxf(v, 0.01f * v);
                        s += w4[r] * v;
                    }
                }
                s += __shfl_xor(s, 16);
                s += __shfl_xor(s, 32);
                if (q == 0) pp[wj][wi * 64 + pg * 16 + l15] = s;
            }
            __syncthreads();
            if (t < 128)
                out[pbase + t] = pp[0][t] + pp[1][t] + tb2_0;
        }
    }
}

extern "C" void kernel_launch(void* const* d_in, const int* in_sizes, int n_in,
                              void* d_out, int out_size, void* d_ws, size_t ws_size,
                              hipStream_t stream) {
    const float* noise  = (const float*)d_in[0];
    const float* coords = (const float*)d_in[1];
    const float* trans  = (const float*)d_in[2];
    const float* ivec   = (const float*)d_in[3];
    const float* lw     = (const float*)d_in[4];
    const float* lb     = (const float*)d_in[5];
    const float* lnw    = (const float*)d_in[6];
    const float* tw1    = (const float*)d_in[7];
    const float* tb1    = (const float*)d_in[8];
    const float* tw2    = (const float*)d_in[9];
    const float* tb2    = (const float*)d_in[10];
    float* o            = (float*)d_out;

    const int N = in_sizes[1] / 2;                    // coords is [N,2]
    // ws layout: nv [32 planes][N] f16 (16 MiB) | wf | waug | quads (16 MiB)
    f16* nv    = (f16*)d_ws;
    const size_t NV = (size_t)N * 32;                 // f16 units
    f16* wfp   = nv + NV;
    f16* waugp = wfp + 5 * 16384;
    f16* qn    = waugp + 5 * 4096;
    const size_t need_full = (NV + 5 * 16384 + 5 * 4096
                              + (size_t)32 * 256 * 256 * 4) * sizeof(f16);

    if (ws_size >= need_full) {   // ws_size constant across calls -> graph-safe
        pack_all_k<<<8192 + 50, 256, 0, stream>>>(noise, qn, lw, lnw, lb, tw1, tb1,
                                                  ivec, wfp, waugp);
        sample_kernel<true><<<(N / 1024) * 8, 256, 0, stream>>>(qn, coords, trans, nv, N);
    } else {
        pack_w_k<<<50, 256, 0, stream>>>(lw, lnw, lb, tw1, tb1, ivec, wfp, waugp);
        sample_kernel<false><<<(N / 1024) * 8, 256, 0, stream>>>(noise, coords, trans, nv, N);
    }
    mlp_kernel<<<N / PTS, 256, 0, stream>>>(nv, wfp, waugp, tw2, tb2, o, N);
}